// Round 2
// baseline (1025.183 us; speedup 1.0000x reference)
//
#include <hip/hip_runtime.h>
#include <hip/hip_bf16.h>

// ---------------- config ----------------
#define DT_BF16 0    // reference is float32 throughout -> fp32 inputs
#define OUT_BF16 0   // fp32 output

#if DT_BF16
typedef __hip_bfloat16 BF;
__device__ __forceinline__ float ldf(const BF* p, int i) { return __bfloat162float(p[i]); }
#else
typedef float BF;
__device__ __forceinline__ float ldf(const BF* p, int i) { return p[i]; }
#endif

typedef _Float16 h8 __attribute__((ext_vector_type(8)));
typedef float f4 __attribute__((ext_vector_type(4)));

static constexpr int N_NODES = 20000;
static constexpr int N_EDGES = 50000;
static constexpr int E_PAD   = 50048;  // 391*128
static constexpr int N_PAD   = 20032;  // 313*64
static constexpr int BROW    = 136;    // padded LDS row (128 + 8 halves) to break bank conflicts

__device__ __forceinline__ float sigf(float x) { return 1.f / (1.f + __expf(-x)); }
__device__ __forceinline__ float tanh_f(float x) {
  float e = __expf(2.f * x);
  return 1.f - 2.f / (e + 1.f);   // robust at +/-inf
}
__device__ __forceinline__ unsigned enc_f(float f) {
  unsigned u = __float_as_uint(f);
  return (u & 0x80000000u) ? ~u : (u | 0x80000000u);
}
__device__ __forceinline__ float dec_f(unsigned u) {
  unsigned b = (u & 0x80000000u) ? (u & 0x7FFFFFFFu) : ~u;
  return __uint_as_float(b);
}

// ---------------- prep kernels ----------------
__global__ void k_lin0(const BF* __restrict__ x, const BF* __restrict__ w0,
                       const BF* __restrict__ b0, float* __restrict__ h) {
  int idx = blockIdx.x * 256 + threadIdx.x;  // (n,o), exact N*64
  int n = idx >> 6, o = idx & 63;
  float acc = ldf(b0, o);
#pragma unroll
  for (int f = 0; f < 16; ++f) acc += ldf(x, n * 16 + f) * ldf(w0, o * 16 + f);
  h[idx] = fmaxf(acc, 0.f);
}

__global__ void k_mlp1(const BF* __restrict__ ea, const BF* __restrict__ w1,
                       const BF* __restrict__ b1, _Float16* __restrict__ hidf) {
  int idx = blockIdx.x * 256 + threadIdx.x;  // (e,j) over E_PAD*128
  int e = idx >> 7, j = idx & 127;
  float v = 0.f;
  if (e < N_EDGES) {
    float acc = ldf(b1, j);
#pragma unroll
    for (int i = 0; i < 5; ++i) acc += ldf(ea, e * 5 + i) * ldf(w1, j * 5 + i);
    v = fmaxf(acc, 0.f);
  }
  hidf[idx] = (_Float16)v;
}

__global__ void k_w2cvt(const BF* __restrict__ w2, _Float16* __restrict__ Q) {
  int i = blockIdx.x * 256 + threadIdx.x;  // 4096*128
  Q[i] = (_Float16)ldf(w2, i);
}

__global__ void k_wcat(const BF* __restrict__ wih, const BF* __restrict__ whh,
                       _Float16* __restrict__ Wcat) {
  int idx = blockIdx.x * 256 + threadIdx.x;  // 256*128
  int row = idx >> 7, k = idx & 127;
  int g = row >> 6, rr = row & 63;
  float v = 0.f;
  if (g == 0) v = (k < 64) ? ldf(wih, rr * 64 + k) : ldf(whh, rr * 64 + (k - 64));
  else if (g == 1) v = (k < 64) ? ldf(wih, (64 + rr) * 64 + k) : ldf(whh, (64 + rr) * 64 + (k - 64));
  else if (g == 2) v = (k < 64) ? ldf(wih, (128 + rr) * 64 + k) : 0.f;
  else v = (k < 64) ? 0.f : ldf(whh, (128 + rr) * 64 + (k - 64));
  Wcat[idx] = (_Float16)v;
}

__global__ void k_bcat(const BF* __restrict__ bih, const BF* __restrict__ bhh,
                       float* __restrict__ bcat) {
  int t = threadIdx.x;  // 256
  float v;
  if (t < 128) v = ldf(bih, t) + ldf(bhh, t);
  else if (t < 192) v = ldf(bih, t);
  else v = ldf(bhh, t - 64);
  bcat[t] = v;
}

__global__ void k_deg(const int* __restrict__ dst, float* __restrict__ deg) {
  int e = blockIdx.x * 256 + threadIdx.x;
  if (e < N_EDGES) atomicAdd(&deg[dst[e]], 1.f);
}

__global__ void k_invdeg(const float* __restrict__ deg, float* __restrict__ inv) {
  int n = blockIdx.x * 256 + threadIdx.x;
  if (n < N_NODES) inv[n] = 1.f / fmaxf(deg[n], 1.f);
}

// ---------------- fused NNConv message kernel ----------------
// msg[e,o] = sum_{d,k} s_e[d]*hidden_e[k]*Q[d*64+o][k]; atomicAdd into agg[dst[e]][o]
// Block: 256 thr = 4 waves; 128 edges/block; wave = 32 edges (2 m-tiles) x 64 outputs.
// blockIdx.y in {0,1} selects d-half [y*32, y*32+32).
__launch_bounds__(256)
__global__ void k_msg(const float* __restrict__ h, const _Float16* __restrict__ hidf,
                      const _Float16* __restrict__ Q, const int* __restrict__ src,
                      const int* __restrict__ dst, float* __restrict__ agg) {
  __shared__ _Float16 s_lds[128 * 33];
  __shared__ _Float16 b_lds[2][64 * BROW];
  const int tid = threadIdx.x;
  const int wv = tid >> 6, ln = tid & 63;
  const int m0 = ln & 15, quad = ln >> 4;
  const int eblk = blockIdx.x * 128;
  const int dbase = blockIdx.y * 32;

  // stage s (gathered src node features, f16), 2 threads per edge
  {
    int el = tid >> 1, dl0 = (tid & 1) * 16;
    int e = eblk + el;
    if (e < N_EDGES) {
      const float* hr = h + (size_t)src[e] * 64 + dbase + dl0;
#pragma unroll
      for (int i = 0; i < 16; ++i) s_lds[el * 33 + dl0 + i] = (_Float16)hr[i];
    } else {
#pragma unroll
      for (int i = 0; i < 16; ++i) s_lds[el * 33 + dl0 + i] = (_Float16)0.f;
    }
  }
  // per-lane hidden registers: 2 m-tiles x 4 k-steps x 8 halves
  h8 hv[2][4];
#pragma unroll
  for (int mt = 0; mt < 2; ++mt) {
    int e = eblk + wv * 32 + mt * 16 + m0;
    const _Float16* hp = hidf + (size_t)e * 128 + quad * 8;
#pragma unroll
    for (int t = 0; t < 4; ++t) hv[mt][t] = *(const h8*)(hp + t * 32);
  }
  // stage B for d-slice 0
  uint4 breg[4];
  {
    const uint4* qs = (const uint4*)(Q + (size_t)dbase * 8192);
#pragma unroll
    for (int c = 0; c < 4; ++c) breg[c] = qs[tid + c * 256];
#pragma unroll
    for (int c = 0; c < 4; ++c) {
      int i = tid + c * 256, r = i >> 4, ch = i & 15;
      *(uint4*)&b_lds[0][r * BROW + ch * 8] = breg[c];
    }
  }
  __syncthreads();

  f4 acc[2][4];
#pragma unroll
  for (int mt = 0; mt < 2; ++mt)
#pragma unroll
    for (int ct = 0; ct < 4; ++ct)
#pragma unroll
      for (int j = 0; j < 4; ++j) acc[mt][ct][j] = 0.f;

  for (int dl = 0; dl < 32; ++dl) {
    int cur = dl & 1;
    if (dl + 1 < 32) {
      const uint4* qs = (const uint4*)(Q + (size_t)(dbase + dl + 1) * 8192);
#pragma unroll
      for (int c = 0; c < 4; ++c) breg[c] = qs[tid + c * 256];
    }
    _Float16 sv0 = s_lds[(wv * 32 + m0) * 33 + dl];
    _Float16 sv1 = s_lds[(wv * 32 + 16 + m0) * 33 + dl];
    const _Float16* bb = &b_lds[cur][0];
#pragma unroll
    for (int t = 0; t < 4; ++t) {
      h8 a0, a1;
#pragma unroll
      for (int j = 0; j < 8; ++j) { a0[j] = hv[0][t][j] * sv0; a1[j] = hv[1][t][j] * sv1; }
#pragma unroll
      for (int ct = 0; ct < 4; ++ct) {
        h8 b = *(const h8*)(bb + (ct * 16 + m0) * BROW + t * 32 + quad * 8);
        acc[0][ct] = __builtin_amdgcn_mfma_f32_16x16x32_f16(a0, b, acc[0][ct], 0, 0, 0);
        acc[1][ct] = __builtin_amdgcn_mfma_f32_16x16x32_f16(a1, b, acc[1][ct], 0, 0, 0);
      }
    }
    if (dl + 1 < 32) {
#pragma unroll
      for (int c = 0; c < 4; ++c) {
        int i = tid + c * 256, r = i >> 4, ch = i & 15;
        *(uint4*)&b_lds[cur ^ 1][r * BROW + ch * 8] = breg[c];
      }
    }
    __syncthreads();
  }
  // epilogue: scatter-add (C layout: col=lane&15 -> o, row=quad*4+reg -> edge)
#pragma unroll
  for (int mt = 0; mt < 2; ++mt) {
#pragma unroll
    for (int r = 0; r < 4; ++r) {
      int e = eblk + wv * 32 + mt * 16 + quad * 4 + r;
      if (e < N_EDGES) {
        float* ap = agg + (size_t)dst[e] * 64 + m0;
#pragma unroll
        for (int ct = 0; ct < 4; ++ct) atomicAdd(ap + ct * 16, acc[mt][ct][r]);
      }
    }
  }
}

// neighbor feature sum for the mlp_b2 term: SS[v][d] = sum_{e: dst=v} h[src[e]][d]
__global__ void k_ss(const float* __restrict__ h, const int* __restrict__ src,
                     const int* __restrict__ dst, float* __restrict__ SS) {
  int e = blockIdx.x * 4 + (threadIdx.x >> 6);
  int o = threadIdx.x & 63;
  if (e < N_EDGES) atomicAdd(&SS[(size_t)dst[e] * 64 + o], h[(size_t)src[e] * 64 + o]);
}

// m = relu((agg + SS@B2)/deg + conv_b);  X = [f16(m) | f16(h)]  (N_PAD rows)
__global__ void k_mh(const float* __restrict__ agg, const float* __restrict__ SS,
                     const float* __restrict__ inv, const BF* __restrict__ convb,
                     const BF* __restrict__ b2, const float* __restrict__ h,
                     _Float16* __restrict__ X) {
  int idx = blockIdx.x * 256 + threadIdx.x;  // (n,j) over N_PAD*128
  int n = idx >> 7, j = idx & 127;
  _Float16 v = (_Float16)0.f;
  if (n < N_NODES) {
    if (j < 64) {
      float bt = 0.f;
      const float* ssr = SS + (size_t)n * 64;
      for (int d = 0; d < 64; ++d) bt += ssr[d] * ldf(b2, d * 64 + j);
      float m = fmaxf((agg[(size_t)n * 64 + j] + bt) * inv[n] + ldf(convb, j), 0.f);
      v = (_Float16)m;
    } else {
      v = (_Float16)h[(size_t)n * 64 + (j - 64)];
    }
  }
  X[idx] = v;
}

// Fused GRU: gates = X[64 rows,128] @ Wcat[256,128]^T + bcat; h = GRU(h, gates).
// One block = 64 node rows x all 256 gate cols; W fully LDS-resident.
// C layout: lane holds (row=quad*4+r, col=ct*16+m0); cols o/o+64/o+128/o+192
// live in the SAME lane at ct=c0, c0+4, c0+8, c0+12 -> gates in-register.
__launch_bounds__(256)
__global__ void k_gru(const _Float16* __restrict__ X, const _Float16* __restrict__ W,
                      const float* __restrict__ bcat, float* __restrict__ h) {
  __shared__ _Float16 xa[64 * BROW];
  __shared__ _Float16 wb[256 * BROW];
  __shared__ float bsh[256];
  int tid = threadIdx.x;
  int wv = tid >> 6, ln = tid & 63, m0 = ln & 15, quad = ln >> 4;
  int rowblk = blockIdx.x * 64;
  bsh[tid] = bcat[tid];
#pragma unroll
  for (int c = 0; c < 4; ++c) {
    int i = tid + c * 256, r = i >> 4, ch = i & 15;
    *(uint4*)&xa[r * BROW + ch * 8] = *(const uint4*)(X + (size_t)(rowblk + r) * 128 + ch * 8);
  }
#pragma unroll
  for (int c = 0; c < 16; ++c) {
    int i = tid + c * 256, r = i >> 4, ch = i & 15;
    *(uint4*)&wb[r * BROW + ch * 8] = *(const uint4*)(W + (size_t)r * 128 + ch * 8);
  }
  __syncthreads();
  f4 acc[16];
#pragma unroll
  for (int ct = 0; ct < 16; ++ct)
#pragma unroll
    for (int j = 0; j < 4; ++j) acc[ct][j] = 0.f;
#pragma unroll
  for (int t = 0; t < 4; ++t) {
    h8 a = *(const h8*)&xa[(wv * 16 + m0) * BROW + t * 32 + quad * 8];
#pragma unroll
    for (int ct = 0; ct < 16; ++ct) {
      h8 b = *(const h8*)&wb[(ct * 16 + m0) * BROW + t * 32 + quad * 8];
      acc[ct] = __builtin_amdgcn_mfma_f32_16x16x32_f16(a, b, acc[ct], 0, 0, 0);
    }
  }
#pragma unroll
  for (int c0 = 0; c0 < 4; ++c0) {
    int o = c0 * 16 + m0;
    float br = bsh[o], bz = bsh[64 + o], bn = bsh[128 + o], bh2 = bsh[192 + o];
#pragma unroll
    for (int r = 0; r < 4; ++r) {
      int row = rowblk + wv * 16 + quad * 4 + r;
      if (row < N_NODES) {
        float rr = sigf(acc[c0][r] + br);
        float zz = sigf(acc[c0 + 4][r] + bz);
        float nn = tanh_f(acc[c0 + 8][r] + bn + rr * (acc[c0 + 12][r] + bh2));
        size_t hi = (size_t)row * 64 + o;
        float hp = h[hi];
        h[hi] = (1.f - zz) * nn + zz * hp;
      }
    }
  }
}

// ---------------- Set2Set ----------------
__global__ void k_lstm(const float* __restrict__ q_star, float* __restrict__ hh,
                       float* __restrict__ cc, const BF* __restrict__ wih,
                       const BF* __restrict__ whh, const BF* __restrict__ bih,
                       const BF* __restrict__ bhh) {
  __shared__ float qrow[128], hrow[64], g[256];
  int b = blockIdx.x, t = threadIdx.x;
  if (t < 128) qrow[t] = q_star[b * 128 + t];
  if (t < 64) hrow[t] = hh[b * 64 + t];
  __syncthreads();
  float acc = ldf(bih, t) + ldf(bhh, t);
  const BF* wr = wih + t * 128;
  for (int i = 0; i < 128; ++i) acc += qrow[i] * ldf(wr, i);
  const BF* wr2 = whh + t * 64;
  for (int i = 0; i < 64; ++i) acc += hrow[i] * ldf(wr2, i);
  g[t] = acc;
  __syncthreads();
  if (t < 64) {
    float ig = sigf(g[t]), fg = sigf(g[64 + t]);
    float gg = tanh_f(g[128 + t]), og = sigf(g[192 + t]);
    float c = fg * cc[b * 64 + t] + ig * gg;
    cc[b * 64 + t] = c;
    hh[b * 64 + t] = og * tanh_f(c);
  }
}

__global__ void k_attn_e(const float* __restrict__ h, const float* __restrict__ hh,
                         const int* __restrict__ batch, float* __restrict__ e_buf,
                         unsigned* __restrict__ emax) {
  int n = blockIdx.x * 4 + (threadIdx.x >> 6);
  int o = threadIdx.x & 63;
  int b = batch[n];
  float p = h[(size_t)n * 64 + o] * hh[b * 64 + o];
#pragma unroll
  for (int off = 32; off > 0; off >>= 1) p += __shfl_xor(p, off);
  if (o == 0) {
    e_buf[n] = p;
    atomicMax(&emax[b], enc_f(p));
  }
}

__global__ void k_attn_a(const float* __restrict__ e_buf, const int* __restrict__ batch,
                         const unsigned* __restrict__ emax, float* __restrict__ a_buf,
                         float* __restrict__ asum) {
  int n = blockIdx.x * 256 + threadIdx.x;
  if (n < N_NODES) {
    int b = batch[n];
    float a = __expf(e_buf[n] - dec_f(emax[b]));
    a_buf[n] = a;
    atomicAdd(&asum[b], a);
  }
}

__global__ void k_attn_r(const float* __restrict__ h, const float* __restrict__ a_buf,
                         const float* __restrict__ asum, const int* __restrict__ batch,
                         float* __restrict__ rbuf) {
  int n = blockIdx.x * 4 + (threadIdx.x >> 6);
  int o = threadIdx.x & 63;
  int b = batch[n];
  float w = a_buf[n] / asum[b];
  atomicAdd(&rbuf[b * 64 + o], w * h[(size_t)n * 64 + o]);
}

__global__ void k_qstar(const float* __restrict__ hh, const float* __restrict__ rbuf,
                        float* __restrict__ q_star) {
  int idx = blockIdx.x * 256 + threadIdx.x;  // 128*128
  int b = idx >> 7, j = idx & 127;
  q_star[idx] = (j < 64) ? hh[b * 64 + j] : rbuf[b * 64 + (j - 64)];
}

#if OUT_BF16
__global__ void k_out(const float* __restrict__ q_star, __hip_bfloat16* __restrict__ outp) {
  int i = blockIdx.x * 256 + threadIdx.x;
  outp[i] = __float2bfloat16(q_star[i]);
}
#else
__global__ void k_out(const float* __restrict__ q_star, float* __restrict__ outp) {
  int i = blockIdx.x * 256 + threadIdx.x;
  outp[i] = q_star[i];
}
#endif

// ---------------- launch ----------------
extern "C" void kernel_launch(void* const* d_in, const int* in_sizes, int n_in,
                              void* d_out, int out_size, void* d_ws, size_t ws_size,
                              hipStream_t stream) {
  const BF* x      = (const BF*)d_in[0];
  const int* ei    = (const int*)d_in[1];
  const BF* ea     = (const BF*)d_in[2];
  const int* batch = (const int*)d_in[3];
  const BF* w0     = (const BF*)d_in[4];
  const BF* b0     = (const BF*)d_in[5];
  const BF* w1     = (const BF*)d_in[6];
  const BF* b1     = (const BF*)d_in[7];
  const BF* w2     = (const BF*)d_in[8];
  const BF* b2     = (const BF*)d_in[9];
  const BF* convb  = (const BF*)d_in[10];
  const BF* gwih   = (const BF*)d_in[11];
  const BF* gwhh   = (const BF*)d_in[12];
  const BF* gbih   = (const BF*)d_in[13];
  const BF* gbhh   = (const BF*)d_in[14];
  const BF* lwih   = (const BF*)d_in[15];
  const BF* lwhh   = (const BF*)d_in[16];
  const BF* lbih   = (const BF*)d_in[17];
  const BF* lbhh   = (const BF*)d_in[18];
  const int* src = ei;
  const int* dstp = ei + N_EDGES;

  char* w = (char*)d_ws;
  size_t off = 0;
  auto take = [&](size_t bytes) -> void* {
    void* p = w + off;
    off = (off + bytes + 255) & ~(size_t)255;
    return p;
  };
  _Float16* Qf16 = (_Float16*)take((size_t)4096 * 128 * 2);
  _Float16* hidf = (_Float16*)take((size_t)E_PAD * 128 * 2);
  float* h       = (float*)take((size_t)N_NODES * 64 * 4);
  float* agg     = (float*)take((size_t)N_NODES * 64 * 4);
  float* SS      = (float*)take((size_t)N_NODES * 64 * 4);   // adjacent to agg -> one memset
  float* invdeg  = (float*)take((size_t)N_NODES * 4);
  float* deg     = (float*)take((size_t)N_NODES * 4);
  _Float16* X    = (_Float16*)take((size_t)N_PAD * 128 * 2);
  _Float16* Wcat = (_Float16*)take((size_t)256 * 128 * 2);
  float* bcat    = (float*)take((size_t)256 * 4);
  float* e_buf   = (float*)take((size_t)N_NODES * 4);
  float* a_buf   = (float*)take((size_t)N_NODES * 4);
  unsigned* emax = (unsigned*)take((size_t)128 * 4);
  float* asum    = (float*)take((size_t)128 * 4);
  float* rbuf    = (float*)take((size_t)128 * 64 * 4);       // emax/asum/rbuf contiguous
  float* q_star  = (float*)take((size_t)128 * 128 * 4);
  float* hh      = (float*)take((size_t)128 * 64 * 4);
  float* cc      = (float*)take((size_t)128 * 64 * 4);       // q_star/hh/cc contiguous

  // ---- prep ----
  k_lin0<<<5000, 256, 0, stream>>>(x, w0, b0, h);
  k_mlp1<<<E_PAD * 128 / 256, 256, 0, stream>>>(ea, w1, b1, hidf);
  k_w2cvt<<<4096 * 128 / 256, 256, 0, stream>>>(w2, Qf16);
  k_wcat<<<128, 256, 0, stream>>>(gwih, gwhh, Wcat);
  k_bcat<<<1, 256, 0, stream>>>(gbih, gbhh, bcat);
  hipMemsetAsync(deg, 0, (size_t)N_NODES * 4, stream);
  k_deg<<<(N_EDGES + 255) / 256, 256, 0, stream>>>(dstp, deg);
  k_invdeg<<<(N_NODES + 255) / 256, 256, 0, stream>>>(deg, invdeg);

  // ---- 3 message-passing iterations ----
  for (int it = 0; it < 3; ++it) {
    hipMemsetAsync(agg, 0, (size_t)2 * N_NODES * 64 * 4, stream);  // agg + SS
    k_msg<<<dim3(E_PAD / 128, 2), 256, 0, stream>>>(h, hidf, Qf16, src, dstp, agg);
    k_ss<<<N_EDGES / 4, 256, 0, stream>>>(h, src, dstp, SS);
    k_mh<<<N_PAD * 128 / 256, 256, 0, stream>>>(agg, SS, invdeg, convb, b2, h, X);
    k_gru<<<N_PAD / 64, 256, 0, stream>>>(X, Wcat, bcat, h);
  }

  // ---- Set2Set (3 steps) ----
  hipMemsetAsync(q_star, 0, (size_t)(128 * 128 + 128 * 64 + 128 * 64) * 4, stream);
  for (int st = 0; st < 3; ++st) {
    k_lstm<<<128, 256, 0, stream>>>(q_star, hh, cc, lwih, lwhh, lbih, lbhh);
    hipMemsetAsync(emax, 0, (size_t)(128 + 128 + 128 * 64) * 4, stream);
    k_attn_e<<<5000, 256, 0, stream>>>(h, hh, batch, e_buf, emax);
    k_attn_a<<<(N_NODES + 255) / 256, 256, 0, stream>>>(e_buf, batch, emax, a_buf, asum);
    k_attn_r<<<5000, 256, 0, stream>>>(h, a_buf, asum, batch, rbuf);
    k_qstar<<<64, 256, 0, stream>>>(hh, rbuf, q_star);
  }
#if OUT_BF16
  k_out<<<64, 256, 0, stream>>>(q_star, (__hip_bfloat16*)d_out);
#else
  k_out<<<64, 256, 0, stream>>>(q_star, (float*)d_out);
#endif
}

// Round 3
// 999.823 us; speedup vs baseline: 1.0254x; 1.0254x over previous
//
#include <hip/hip_runtime.h>
#include <hip/hip_bf16.h>

typedef float BF;
__device__ __forceinline__ float ldf(const BF* p, int i) { return p[i]; }

typedef _Float16 h8 __attribute__((ext_vector_type(8)));
typedef float f4 __attribute__((ext_vector_type(4)));

static constexpr int N_NODES = 20000;
static constexpr int N_EDGES = 50000;
static constexpr int E_PAD   = 50048;  // 391*128
static constexpr int N_PAD   = 20032;  // 313*64
static constexpr int BROW    = 136;    // padded LDS row (128+8 halves)
static constexpr int ROWP    = 72;     // padded LDS row for 64-wide tiles
static constexpr int MAXSEG  = 2048;   // >> max segment of sorted batch (mean 156)

__device__ __forceinline__ float sigf(float x) { return 1.f / (1.f + __expf(-x)); }
__device__ __forceinline__ float tanh_f(float x) {
  float e = __expf(2.f * x);
  return 1.f - 2.f / (e + 1.f);
}

// ---------------- prep kernels ----------------
__global__ void k_lin0(const BF* __restrict__ x, const BF* __restrict__ w0,
                       const BF* __restrict__ b0, float* __restrict__ h) {
  int idx = blockIdx.x * 256 + threadIdx.x;  // exact N*64
  int n = idx >> 6, o = idx & 63;
  float acc = ldf(b0, o);
#pragma unroll
  for (int f = 0; f < 16; ++f) acc += ldf(x, n * 16 + f) * ldf(w0, o * 16 + f);
  h[idx] = fmaxf(acc, 0.f);
}

__global__ void k_mlp1(const BF* __restrict__ ea, const BF* __restrict__ w1,
                       const BF* __restrict__ b1, _Float16* __restrict__ hidf) {
  int idx = blockIdx.x * 256 + threadIdx.x;  // E_PAD*128
  int e = idx >> 7, j = idx & 127;
  float v = 0.f;
  if (e < N_EDGES) {
    float acc = ldf(b1, j);
#pragma unroll
    for (int i = 0; i < 5; ++i) acc += ldf(ea, e * 5 + i) * ldf(w1, j * 5 + i);
    v = fmaxf(acc, 0.f);
  }
  hidf[idx] = (_Float16)v;
}

__global__ void k_w2cvt(const BF* __restrict__ w2, _Float16* __restrict__ Q) {
  int i = blockIdx.x * 256 + threadIdx.x;  // 4096*128
  Q[i] = (_Float16)ldf(w2, i);
}

__global__ void k_wcat(const BF* __restrict__ wih, const BF* __restrict__ whh,
                       _Float16* __restrict__ Wcat) {
  int idx = blockIdx.x * 256 + threadIdx.x;  // 256*128
  int row = idx >> 7, k = idx & 127;
  int g = row >> 6, rr = row & 63;
  float v = 0.f;
  if (g == 0) v = (k < 64) ? ldf(wih, rr * 64 + k) : ldf(whh, rr * 64 + (k - 64));
  else if (g == 1) v = (k < 64) ? ldf(wih, (64 + rr) * 64 + k) : ldf(whh, (64 + rr) * 64 + (k - 64));
  else if (g == 2) v = (k < 64) ? ldf(wih, (128 + rr) * 64 + k) : 0.f;
  else v = (k < 64) ? 0.f : ldf(whh, (128 + rr) * 64 + (k - 64));
  Wcat[idx] = (_Float16)v;
}

__global__ void k_bcat(const BF* __restrict__ bih, const BF* __restrict__ bhh,
                       float* __restrict__ bcat) {
  int t = threadIdx.x;
  float v;
  if (t < 128) v = ldf(bih, t) + ldf(bhh, t);
  else if (t < 192) v = ldf(bih, t);
  else v = ldf(bhh, t - 64);
  bcat[t] = v;
}

__global__ void k_deg(const int* __restrict__ dst, float* __restrict__ deg) {
  int e = blockIdx.x * 256 + threadIdx.x;
  if (e < N_EDGES) atomicAdd(&deg[dst[e]], 1.f);
}

// segment starts of the (sorted) batch vector
__global__ void k_seg(const int* __restrict__ batch, int* __restrict__ seg) {
  int b = threadIdx.x;  // 256 threads, use 0..128
  if (b > 128) return;
  if (b == 128) { seg[128] = N_NODES; return; }
  int lo = 0, hi = N_NODES;
  while (lo < hi) {
    int mid = (lo + hi) >> 1;
    if (batch[mid] < b) lo = mid + 1; else hi = mid;
  }
  seg[b] = lo;
}

// ---------------- fused NNConv message kernel ----------------
// msg[e,o] = sum_{d,k} s_e[d]*hidden_e[k]*Q[d*64+o][k]; atomicAdd into agg[dst[e]]
// Also folds the SS neighbor-sum (for the mlp_b2 term) into the staging pass.
__launch_bounds__(256)
__global__ void k_msg(const float* __restrict__ h, const _Float16* __restrict__ hidf,
                      const _Float16* __restrict__ Q, const int* __restrict__ src,
                      const int* __restrict__ dst, float* __restrict__ agg,
                      float* __restrict__ SS) {
  __shared__ _Float16 s_lds[128 * 33];
  __shared__ _Float16 b_lds[2][64 * BROW];
  const int tid = threadIdx.x;
  const int wv = tid >> 6, ln = tid & 63;
  const int m0 = ln & 15, quad = ln >> 4;
  const int eblk = blockIdx.x * 128;
  const int dbase = blockIdx.y * 32;

  // stage s (gathered src feats -> f16 LDS) + SS scatter (fp32), 2 thr/edge
  {
    int el = tid >> 1, dl0 = (tid & 1) * 16;
    int e = eblk + el;
    if (e < N_EDGES) {
      const float* hr = h + (size_t)src[e] * 64 + dbase + dl0;
      float* ssp = SS + (size_t)dst[e] * 64 + dbase + dl0;
#pragma unroll
      for (int i = 0; i < 16; ++i) {
        float v = hr[i];
        s_lds[el * 33 + dl0 + i] = (_Float16)v;
        atomicAdd(ssp + i, v);
      }
    } else {
#pragma unroll
      for (int i = 0; i < 16; ++i) s_lds[el * 33 + dl0 + i] = (_Float16)0.f;
    }
  }
  // per-lane hidden regs: 2 m-tiles x 4 k-steps x 8 halves
  h8 hv[2][4];
#pragma unroll
  for (int mt = 0; mt < 2; ++mt) {
    int e = eblk + wv * 32 + mt * 16 + m0;
    const _Float16* hp = hidf + (size_t)e * 128 + quad * 8;
#pragma unroll
    for (int t = 0; t < 4; ++t) hv[mt][t] = *(const h8*)(hp + t * 32);
  }
  uint4 breg[4];
  {
    const uint4* qs = (const uint4*)(Q + (size_t)dbase * 8192);
#pragma unroll
    for (int c = 0; c < 4; ++c) breg[c] = qs[tid + c * 256];
#pragma unroll
    for (int c = 0; c < 4; ++c) {
      int i = tid + c * 256, r = i >> 4, ch = i & 15;
      *(uint4*)&b_lds[0][r * BROW + ch * 8] = breg[c];
    }
  }
  __syncthreads();

  f4 acc[2][4];
#pragma unroll
  for (int mt = 0; mt < 2; ++mt)
#pragma unroll
    for (int ct = 0; ct < 4; ++ct)
#pragma unroll
      for (int j = 0; j < 4; ++j) acc[mt][ct][j] = 0.f;

  for (int dl = 0; dl < 32; ++dl) {
    int cur = dl & 1;
    if (dl + 1 < 32) {
      const uint4* qs = (const uint4*)(Q + (size_t)(dbase + dl + 1) * 8192);
#pragma unroll
      for (int c = 0; c < 4; ++c) breg[c] = qs[tid + c * 256];
    }
    _Float16 sv0 = s_lds[(wv * 32 + m0) * 33 + dl];
    _Float16 sv1 = s_lds[(wv * 32 + 16 + m0) * 33 + dl];
    const _Float16* bb = &b_lds[cur][0];
#pragma unroll
    for (int t = 0; t < 4; ++t) {
      h8 a0, a1;
#pragma unroll
      for (int j = 0; j < 8; ++j) { a0[j] = hv[0][t][j] * sv0; a1[j] = hv[1][t][j] * sv1; }
#pragma unroll
      for (int ct = 0; ct < 4; ++ct) {
        h8 b = *(const h8*)(bb + (ct * 16 + m0) * BROW + t * 32 + quad * 8);
        acc[0][ct] = __builtin_amdgcn_mfma_f32_16x16x32_f16(a0, b, acc[0][ct], 0, 0, 0);
        acc[1][ct] = __builtin_amdgcn_mfma_f32_16x16x32_f16(a1, b, acc[1][ct], 0, 0, 0);
      }
    }
    if (dl + 1 < 32) {
#pragma unroll
      for (int c = 0; c < 4; ++c) {
        int i = tid + c * 256, r = i >> 4, ch = i & 15;
        *(uint4*)&b_lds[cur ^ 1][r * BROW + ch * 8] = breg[c];
      }
    }
    __syncthreads();
  }
#pragma unroll
  for (int mt = 0; mt < 2; ++mt) {
#pragma unroll
    for (int r = 0; r < 4; ++r) {
      int e = eblk + wv * 32 + mt * 16 + quad * 4 + r;
      if (e < N_EDGES) {
        float* ap = agg + (size_t)dst[e] * 64 + m0;
#pragma unroll
        for (int ct = 0; ct < 4; ++ct) atomicAdd(ap + ct * 16, acc[mt][ct][r]);
      }
    }
  }
}

// ---------------- m + X pack: T = SS@B2 (MFMA), m = relu((agg+T)/deg + cb) ----
// block = 64 nodes; X = [f16(m) | f16(h)] rows to N_PAD (pad rows zeroed)
__launch_bounds__(256)
__global__ void k_mh2(const float* __restrict__ SS, const float* __restrict__ agg,
                      const float* __restrict__ deg, const BF* __restrict__ convb,
                      const BF* __restrict__ b2, const float* __restrict__ h,
                      _Float16* __restrict__ X) {
  __shared__ _Float16 ssa[64 * ROWP];   // A: rows=node, cols=d
  __shared__ _Float16 bT[64 * ROWP];    // B^T: rows=o, cols=d
  int tid = threadIdx.x;
  int wv = tid >> 6, ln = tid & 63, m0 = ln & 15, quad = ln >> 4;
  int rowblk = blockIdx.x * 64;
  // stage A (SS -> f16) and upper-X copy source rows
  {
    int r = tid >> 2, c0 = (tid & 3) * 16;
    int node = rowblk + r;
    if (node < N_NODES) {
      const float* sp = SS + (size_t)node * 64 + c0;
#pragma unroll
      for (int i = 0; i < 16; ++i) ssa[r * ROWP + c0 + i] = (_Float16)sp[i];
      const float* hp = h + (size_t)node * 64 + c0;
#pragma unroll
      for (int i = 0; i < 16; ++i) X[(size_t)node * 128 + 64 + c0 + i] = (_Float16)hp[i];
    } else {
#pragma unroll
      for (int i = 0; i < 16; ++i) ssa[r * ROWP + c0 + i] = (_Float16)0.f;
#pragma unroll
      for (int i = 0; i < 16; ++i) X[(size_t)node * 128 + 64 + c0 + i] = (_Float16)0.f;
    }
  }
  // stage B2^T: bT[o][d] = b2[d*64+o]
  {
    int o = tid & 63, d0 = (tid >> 6) * 16;
#pragma unroll
    for (int i = 0; i < 16; ++i) bT[o * ROWP + d0 + i] = (_Float16)ldf(b2, (d0 + i) * 64 + o);
  }
  __syncthreads();
  f4 acc[4];
#pragma unroll
  for (int ct = 0; ct < 4; ++ct)
#pragma unroll
    for (int j = 0; j < 4; ++j) acc[ct][j] = 0.f;
#pragma unroll
  for (int t = 0; t < 2; ++t) {
    h8 a = *(const h8*)&ssa[(wv * 16 + m0) * ROWP + t * 32 + quad * 8];
#pragma unroll
    for (int ct = 0; ct < 4; ++ct) {
      h8 b = *(const h8*)&bT[(ct * 16 + m0) * ROWP + t * 32 + quad * 8];
      acc[ct] = __builtin_amdgcn_mfma_f32_16x16x32_f16(a, b, acc[ct], 0, 0, 0);
    }
  }
  // epilogue: C layout col=ct*16+m0, row=quad*4+r within wave's 16-row tile
#pragma unroll
  for (int ct = 0; ct < 4; ++ct) {
    int o = ct * 16 + m0;
    float cb = ldf(convb, o);
#pragma unroll
    for (int r = 0; r < 4; ++r) {
      int node = rowblk + wv * 16 + quad * 4 + r;
      _Float16 v = (_Float16)0.f;
      if (node < N_NODES) {
        float inv = 1.f / fmaxf(deg[node], 1.f);
        float m = fmaxf((agg[(size_t)node * 64 + o] + acc[ct][r]) * inv + cb, 0.f);
        v = (_Float16)m;
      }
      X[(size_t)node * 128 + o] = v;
    }
  }
}

// ---------------- fused GRU ----------------
__launch_bounds__(256)
__global__ void k_gru(const _Float16* __restrict__ X, const _Float16* __restrict__ W,
                      const float* __restrict__ bcat, float* __restrict__ h) {
  __shared__ _Float16 xa[64 * BROW];
  __shared__ _Float16 wb[256 * BROW];
  __shared__ float bsh[256];
  int tid = threadIdx.x;
  int wv = tid >> 6, ln = tid & 63, m0 = ln & 15, quad = ln >> 4;
  int rowblk = blockIdx.x * 64;
  bsh[tid] = bcat[tid];
#pragma unroll
  for (int c = 0; c < 4; ++c) {
    int i = tid + c * 256, r = i >> 4, ch = i & 15;
    *(uint4*)&xa[r * BROW + ch * 8] = *(const uint4*)(X + (size_t)(rowblk + r) * 128 + ch * 8);
  }
#pragma unroll
  for (int c = 0; c < 16; ++c) {
    int i = tid + c * 256, r = i >> 4, ch = i & 15;
    *(uint4*)&wb[r * BROW + ch * 8] = *(const uint4*)(W + (size_t)r * 128 + ch * 8);
  }
  __syncthreads();
  f4 acc[16];
#pragma unroll
  for (int ct = 0; ct < 16; ++ct)
#pragma unroll
    for (int j = 0; j < 4; ++j) acc[ct][j] = 0.f;
#pragma unroll
  for (int t = 0; t < 4; ++t) {
    h8 a = *(const h8*)&xa[(wv * 16 + m0) * BROW + t * 32 + quad * 8];
#pragma unroll
    for (int ct = 0; ct < 16; ++ct) {
      h8 b = *(const h8*)&wb[(ct * 16 + m0) * BROW + t * 32 + quad * 8];
      acc[ct] = __builtin_amdgcn_mfma_f32_16x16x32_f16(a, b, acc[ct], 0, 0, 0);
    }
  }
#pragma unroll
  for (int c0 = 0; c0 < 4; ++c0) {
    int o = c0 * 16 + m0;
    float br = bsh[o], bz = bsh[64 + o], bn = bsh[128 + o], bh2 = bsh[192 + o];
#pragma unroll
    for (int r = 0; r < 4; ++r) {
      int row = rowblk + wv * 16 + quad * 4 + r;
      if (row < N_NODES) {
        float rr = sigf(acc[c0][r] + br);
        float zz = sigf(acc[c0 + 4][r] + bz);
        float nn = tanh_f(acc[c0 + 8][r] + bn + rr * (acc[c0 + 12][r] + bh2));
        size_t hi = (size_t)row * 64 + o;
        float hp = h[hi];
        h[hi] = (1.f - zz) * nn + zz * hp;
      }
    }
  }
}

// ---------------- fused Set2Set step: LSTM + segment softmax attention --------
// one block per graph b. q = hh identity (seq_len 1) -> no q_star buffer.
__launch_bounds__(256)
__global__ void k_s2s(const float* __restrict__ h, const int* __restrict__ seg,
                      const BF* __restrict__ wih, const BF* __restrict__ whh,
                      const BF* __restrict__ bih, const BF* __restrict__ bhh,
                      float* __restrict__ hh, float* __restrict__ cc,
                      const float* __restrict__ rprev, float* __restrict__ rout) {
  __shared__ float xrow[128], g[256], qrow[64];
  __shared__ float evals[MAXSEG];
  __shared__ float wred[4], rpart[256];
  int b = blockIdx.x, t = threadIdx.x;
  // LSTM input x = [hh, rprev]
  if (t < 64) xrow[t] = hh[b * 64 + t];
  else if (t < 128) xrow[t] = rprev[b * 64 + (t - 64)];
  __syncthreads();
  {
    float acc = ldf(bih, t) + ldf(bhh, t);
    const BF* wr = wih + t * 128;
    for (int i = 0; i < 128; ++i) acc += xrow[i] * ldf(wr, i);
    const BF* wr2 = whh + t * 64;
    for (int i = 0; i < 64; ++i) acc += xrow[i] * ldf(wr2, i);
    g[t] = acc;
  }
  __syncthreads();
  if (t < 64) {
    float ig = sigf(g[t]), fg = sigf(g[64 + t]);
    float gg = tanh_f(g[128 + t]), og = sigf(g[192 + t]);
    float c = fg * cc[b * 64 + t] + ig * gg;
    cc[b * 64 + t] = c;
    float hn = og * tanh_f(c);
    hh[b * 64 + t] = hn;
    qrow[t] = hn;
  }
  __syncthreads();
  int start = seg[b], end = seg[b + 1];
  int cnt = end - start;
  int wv = t >> 6, ln = t & 63;
  // pass 1: e_n = h[n] . q  (wave per node), wave-local max
  float mw = -3.4e38f;
  for (int n = start + wv; n < end; n += 4) {
    float p = h[(size_t)n * 64 + ln] * qrow[ln];
#pragma unroll
    for (int off = 32; off > 0; off >>= 1) p += __shfl_xor(p, off);
    if (ln == 0) evals[n - start] = p;
    mw = fmaxf(mw, p);
  }
  if (ln == 0) wred[wv] = mw;
  __syncthreads();
  float gmax = fmaxf(fmaxf(wred[0], wred[1]), fmaxf(wred[2], wred[3]));
  // pass 2: exp + block sum
  float psum = 0.f;
  for (int i = t; i < cnt; i += 256) {
    float a = __expf(evals[i] - gmax);
    evals[i] = a;
    psum += a;
  }
#pragma unroll
  for (int off = 32; off > 0; off >>= 1) psum += __shfl_xor(psum, off);
  if (ln == 0) wred[wv] = psum;
  __syncthreads();
  float inv = 1.f / fmaxf(wred[0] + wred[1] + wred[2] + wred[3], 1e-30f);
  // pass 3: r = sum a_n h[n] / asum
  float racc = 0.f;
  for (int n = start + wv; n < end; n += 4)
    racc += evals[n - start] * h[(size_t)n * 64 + ln];
  rpart[wv * 64 + ln] = racc;
  __syncthreads();
  if (t < 64)
    rout[b * 64 + t] = (rpart[t] + rpart[64 + t] + rpart[128 + t] + rpart[192 + t]) * inv;
}

__global__ void k_out(const float* __restrict__ hh, const float* __restrict__ rlast,
                      float* __restrict__ outp) {
  int idx = blockIdx.x * 256 + threadIdx.x;  // 128*128
  int b = idx >> 7, j = idx & 127;
  outp[idx] = (j < 64) ? hh[b * 64 + j] : rlast[b * 64 + (j - 64)];
}

// ---------------- launch ----------------
extern "C" void kernel_launch(void* const* d_in, const int* in_sizes, int n_in,
                              void* d_out, int out_size, void* d_ws, size_t ws_size,
                              hipStream_t stream) {
  const BF* x      = (const BF*)d_in[0];
  const int* ei    = (const int*)d_in[1];
  const BF* ea     = (const BF*)d_in[2];
  const int* batch = (const int*)d_in[3];
  const BF* w0     = (const BF*)d_in[4];
  const BF* b0     = (const BF*)d_in[5];
  const BF* w1     = (const BF*)d_in[6];
  const BF* b1     = (const BF*)d_in[7];
  const BF* w2     = (const BF*)d_in[8];
  const BF* b2     = (const BF*)d_in[9];
  const BF* convb  = (const BF*)d_in[10];
  const BF* gwih   = (const BF*)d_in[11];
  const BF* gwhh   = (const BF*)d_in[12];
  const BF* gbih   = (const BF*)d_in[13];
  const BF* gbhh   = (const BF*)d_in[14];
  const BF* lwih   = (const BF*)d_in[15];
  const BF* lwhh   = (const BF*)d_in[16];
  const BF* lbih   = (const BF*)d_in[17];
  const BF* lbhh   = (const BF*)d_in[18];
  const int* src = ei;
  const int* dstp = ei + N_EDGES;

  char* w = (char*)d_ws;
  size_t off = 0;
  auto take = [&](size_t bytes) -> void* {
    void* p = w + off;
    off = (off + bytes + 255) & ~(size_t)255;
    return p;
  };
  _Float16* Qf16 = (_Float16*)take((size_t)4096 * 128 * 2);
  _Float16* hidf = (_Float16*)take((size_t)E_PAD * 128 * 2);
  float* h       = (float*)take((size_t)N_NODES * 64 * 4);
  float* agg     = (float*)take((size_t)N_NODES * 64 * 4);   // agg+SS contiguous
  float* SS      = (float*)take((size_t)N_NODES * 64 * 4);
  float* deg     = (float*)take((size_t)N_NODES * 4);
  _Float16* X    = (_Float16*)take((size_t)N_PAD * 128 * 2);
  _Float16* Wcat = (_Float16*)take((size_t)256 * 128 * 2);
  float* bcat    = (float*)take((size_t)256 * 4);
  int*   seg     = (int*)take((size_t)129 * 4);
  float* hh      = (float*)take((size_t)128 * 64 * 4);       // hh,cc,rzero,rbuf contiguous
  float* cc      = (float*)take((size_t)128 * 64 * 4);
  float* rzero   = (float*)take((size_t)128 * 64 * 4);
  float* rbuf    = (float*)take((size_t)3 * 128 * 64 * 4);

  // ---- prep ----
  k_lin0<<<5000, 256, 0, stream>>>(x, w0, b0, h);
  k_mlp1<<<E_PAD * 128 / 256, 256, 0, stream>>>(ea, w1, b1, hidf);
  k_w2cvt<<<4096 * 128 / 256, 256, 0, stream>>>(w2, Qf16);
  k_wcat<<<128, 256, 0, stream>>>(gwih, gwhh, Wcat);
  k_bcat<<<1, 256, 0, stream>>>(gbih, gbhh, bcat);
  hipMemsetAsync(deg, 0, (size_t)N_NODES * 4, stream);
  k_deg<<<(N_EDGES + 255) / 256, 256, 0, stream>>>(dstp, deg);
  k_seg<<<1, 256, 0, stream>>>(batch, seg);

  // ---- 3 message-passing iterations ----
  for (int it = 0; it < 3; ++it) {
    hipMemsetAsync(agg, 0, (size_t)2 * N_NODES * 64 * 4, stream);  // agg + SS
    k_msg<<<dim3(E_PAD / 128, 2), 256, 0, stream>>>(h, hidf, Qf16, src, dstp, agg, SS);
    k_mh2<<<N_PAD / 64, 256, 0, stream>>>(SS, agg, deg, convb, b2, h, X);
    k_gru<<<N_PAD / 64, 256, 0, stream>>>(X, Wcat, bcat, h);
  }

  // ---- Set2Set (3 fused steps) ----
  hipMemsetAsync(hh, 0, (size_t)(128 * 64 * 6) * 4, stream);  // hh,cc,rzero,rbuf
  for (int st = 0; st < 3; ++st) {
    const float* rp = (st == 0) ? rzero : (rbuf + (size_t)(st - 1) * 8192);
    k_s2s<<<128, 256, 0, stream>>>(h, seg, lwih, lwhh, lbih, lbhh,
                                   hh, cc, rp, rbuf + (size_t)st * 8192);
  }
  k_out<<<64, 256, 0, stream>>>(hh, rbuf + (size_t)2 * 8192, (float*)d_out);
}

// Round 4
// 575.428 us; speedup vs baseline: 1.7816x; 1.7375x over previous
//
#include <hip/hip_runtime.h>
#include <hip/hip_bf16.h>

typedef float BF;
__device__ __forceinline__ float ldf(const BF* p, int i) { return p[i]; }

typedef _Float16 h8 __attribute__((ext_vector_type(8)));
typedef float f4 __attribute__((ext_vector_type(4)));

static constexpr int N_NODES = 20000;
static constexpr int N_EDGES = 50000;
static constexpr int E_PAD   = 50176;  // 196*256
static constexpr int N_PAD   = 20032;  // 313*64
static constexpr int BROW    = 136;    // k_gru LDS row (128+8 halves)
static constexpr int ROWP    = 72;     // k_msg B-tile row (64+8 halves)
static constexpr int SROW    = 40;     // k_msg s-tile row (32+8 halves), 80B = 16B-aligned
static constexpr int MAXSEG  = 2048;

__device__ __forceinline__ float sigf(float x) { return 1.f / (1.f + __expf(-x)); }
__device__ __forceinline__ float tanh_f(float x) {
  float e = __expf(2.f * x);
  return 1.f - 2.f / (e + 1.f);
}

// ================= mega-prep: 8 sections by blockIdx =================
static constexpr int S_LIN0 = 5000;                 // N*64/256
static constexpr int S_MLP1 = E_PAD * 128 / 256;    // 25088
static constexpr int S_W2   = 2048;                 // 4096*128/256
static constexpr int S_WCAT = 128;                  // 256*128/256
static constexpr int S_B2T  = 16;                   // 2*64*32/256
static constexpr int S_DEG  = 196;                  // 50176/256
static constexpr int PREP_BLOCKS = S_LIN0 + S_MLP1 + S_W2 + S_WCAT + S_B2T + 1 + 1 + S_DEG;

__global__ void k_prep(const BF* __restrict__ x, const BF* __restrict__ ea,
                       const int* __restrict__ batch, const int* __restrict__ dst,
                       const BF* __restrict__ w0, const BF* __restrict__ b0,
                       const BF* __restrict__ w1, const BF* __restrict__ b1,
                       const BF* __restrict__ w2, const BF* __restrict__ b2,
                       const BF* __restrict__ gwih, const BF* __restrict__ gwhh,
                       const BF* __restrict__ gbih, const BF* __restrict__ gbhh,
                       float* __restrict__ h, _Float16* __restrict__ hidf,
                       _Float16* __restrict__ Q, _Float16* __restrict__ Wcat,
                       float* __restrict__ bcat, _Float16* __restrict__ b2t,
                       int* __restrict__ seg, float* __restrict__ deg) {
  int bid = blockIdx.x, t = threadIdx.x;
  if (bid < S_LIN0) {                       // lin0: h = relu(x@w0^T + b0)
    int idx = bid * 256 + t, n = idx >> 6, o = idx & 63;
    float acc = ldf(b0, o);
#pragma unroll
    for (int f = 0; f < 16; ++f) acc += ldf(x, n * 16 + f) * ldf(w0, o * 16 + f);
    h[idx] = fmaxf(acc, 0.f);
    return;
  }
  bid -= S_LIN0;
  if (bid < S_MLP1) {                       // edge MLP layer1 -> f16
    int idx = bid * 256 + t, e = idx >> 7, j = idx & 127;
    float v = 0.f;
    if (e < N_EDGES) {
      float acc = ldf(b1, j);
#pragma unroll
      for (int i = 0; i < 5; ++i) acc += ldf(ea, e * 5 + i) * ldf(w1, j * 5 + i);
      v = fmaxf(acc, 0.f);
    }
    hidf[idx] = (_Float16)v;
    return;
  }
  bid -= S_MLP1;
  if (bid < S_W2) {                         // w2 -> f16
    int i = bid * 256 + t;
    Q[i] = (_Float16)ldf(w2, i);
    return;
  }
  bid -= S_W2;
  if (bid < S_WCAT) {                       // GRU weight pack [r|z|n_i|n_h] x [x|h]
    int idx = bid * 256 + t, row = idx >> 7, k = idx & 127;
    int g = row >> 6, rr = row & 63;
    float v = 0.f;
    if (g == 0) v = (k < 64) ? ldf(gwih, rr * 64 + k) : ldf(gwhh, rr * 64 + (k - 64));
    else if (g == 1) v = (k < 64) ? ldf(gwih, (64 + rr) * 64 + k) : ldf(gwhh, (64 + rr) * 64 + (k - 64));
    else if (g == 2) v = (k < 64) ? ldf(gwih, (128 + rr) * 64 + k) : 0.f;
    else v = (k < 64) ? 0.f : ldf(gwhh, (128 + rr) * 64 + (k - 64));
    Wcat[idx] = (_Float16)v;
    return;
  }
  bid -= S_WCAT;
  if (bid < S_B2T) {                        // b2t[y][o*32+kk] = b2[(y*32+kk)*64+o]
    int idx = bid * 256 + t;
    int y = idx >> 11, rem = idx & 2047, o = rem >> 5, kk = rem & 31;
    b2t[idx] = (_Float16)ldf(b2, (y * 32 + kk) * 64 + o);
    return;
  }
  bid -= S_B2T;
  if (bid == 0) {                           // bcat
    float v;
    if (t < 128) v = ldf(gbih, t) + ldf(gbhh, t);
    else if (t < 192) v = ldf(gbih, t);
    else v = ldf(gbhh, t - 64);
    bcat[t] = v;
    return;
  }
  bid -= 1;
  if (bid == 0) {                           // seg starts (batch sorted)
    if (t > 128) return;
    if (t == 128) { seg[128] = N_NODES; return; }
    int lo = 0, hi = N_NODES;
    while (lo < hi) {
      int mid = (lo + hi) >> 1;
      if (batch[mid] < t) lo = mid + 1; else hi = mid;
    }
    seg[t] = lo;
    return;
  }
  bid -= 1;
  {                                         // deg atomics (deg pre-zeroed by memset)
    int e = bid * 256 + t;
    if (e < N_EDGES) atomicAdd(&deg[dst[e]], 1.f);
  }
}

// ================= fused NNConv message kernel v3 =================
// grid (196, 2, 2): y = d-half (dbase=y*32), z = k-half (kbase=z*64).
// block 256 = 4 waves x 64 edges; wave = 4 m-tiles of 16 edges, full 64 outputs.
// b2 term folded as one extra K-step (A = s, B = b2^T) on z==0 blocks.
__launch_bounds__(256)
__global__ void k_msg(const float* __restrict__ h, const _Float16* __restrict__ hidf,
                      const _Float16* __restrict__ Q, const _Float16* __restrict__ b2t,
                      const int* __restrict__ src, const int* __restrict__ dst,
                      float* __restrict__ agg) {
  __shared__ _Float16 s_lds[256 * SROW];
  __shared__ _Float16 b_lds[2][64 * ROWP];
  const int tid = threadIdx.x;
  const int wv = tid >> 6, ln = tid & 63;
  const int m0 = ln & 15, quad = ln >> 4;
  const int eblk = blockIdx.x * 256;
  const int dbase = blockIdx.y * 32;
  const int kbase = blockIdx.z * 64;
  const bool do_b2 = (blockIdx.z == 0);

  // ---- stage s: one thread per edge, 32 d-cols of this half, f16 ----
  {
    int e = eblk + tid;
    _Float16 sv[32];
    if (e < N_EDGES) {
      const float4* hr = (const float4*)(h + (size_t)src[e] * 64 + dbase);
#pragma unroll
      for (int c = 0; c < 8; ++c) {
        float4 f = hr[c];
        sv[c * 4 + 0] = (_Float16)f.x; sv[c * 4 + 1] = (_Float16)f.y;
        sv[c * 4 + 2] = (_Float16)f.z; sv[c * 4 + 3] = (_Float16)f.w;
      }
    } else {
#pragma unroll
      for (int i = 0; i < 32; ++i) sv[i] = (_Float16)0.f;
    }
#pragma unroll
    for (int c = 0; c < 4; ++c)
      *(uint4*)&s_lds[tid * SROW + c * 8] = *(const uint4*)&sv[c * 8];
  }
  // ---- per-lane hidden fragments: 4 m-tiles x 2 k-steps ----
  h8 hv[4][2];
#pragma unroll
  for (int mt = 0; mt < 4; ++mt) {
    int e = eblk + wv * 64 + mt * 16 + m0;
    const _Float16* hp = hidf + (size_t)e * 128 + kbase + quad * 8;
    hv[mt][0] = *(const h8*)hp;
    hv[mt][1] = *(const h8*)(hp + 32);
  }
  // ---- stage B-tile for dl=0: 64 o x 64 k ----
  uint4 breg[2];
  {
    const _Float16* qb = Q + (size_t)dbase * 8192 + kbase;
#pragma unroll
    for (int c = 0; c < 2; ++c) {
      int i = tid + c * 256, r = i >> 3, ch = i & 7;
      breg[c] = *(const uint4*)(qb + (size_t)r * 128 + ch * 8);
    }
#pragma unroll
    for (int c = 0; c < 2; ++c) {
      int i = tid + c * 256, r = i >> 3, ch = i & 7;
      *(uint4*)&b_lds[0][r * ROWP + ch * 8] = breg[c];
    }
  }
  __syncthreads();

  f4 acc[4][4];
#pragma unroll
  for (int mt = 0; mt < 4; ++mt)
#pragma unroll
    for (int ct = 0; ct < 4; ++ct)
#pragma unroll
      for (int j = 0; j < 4; ++j) acc[mt][ct][j] = 0.f;

  for (int dl = 0; dl < 32; ++dl) {
    int cur = dl & 1;
    if (dl + 1 < 32) {
      const _Float16* qb = Q + (size_t)(dbase + dl + 1) * 8192 + kbase;
#pragma unroll
      for (int c = 0; c < 2; ++c) {
        int i = tid + c * 256, r = i >> 3, ch = i & 7;
        breg[c] = *(const uint4*)(qb + (size_t)r * 128 + ch * 8);
      }
    } else if (do_b2) {
      int r = tid >> 2, ch = tid & 3;
      breg[0] = *(const uint4*)(b2t + dbase * 64 + r * 32 + ch * 8);
    }
    _Float16 sv[4];
#pragma unroll
    for (int mt = 0; mt < 4; ++mt)
      sv[mt] = s_lds[(wv * 64 + mt * 16 + m0) * SROW + dl];
#pragma unroll
    for (int t = 0; t < 2; ++t) {
      h8 a[4];
#pragma unroll
      for (int mt = 0; mt < 4; ++mt) a[mt] = hv[mt][t] * sv[mt];
#pragma unroll
      for (int ct = 0; ct < 4; ++ct) {
        h8 b = *(const h8*)&b_lds[cur][(ct * 16 + m0) * ROWP + t * 32 + quad * 8];
#pragma unroll
        for (int mt = 0; mt < 4; ++mt)
          acc[mt][ct] = __builtin_amdgcn_mfma_f32_16x16x32_f16(a[mt], b, acc[mt][ct], 0, 0, 0);
      }
    }
    if (dl + 1 < 32) {
#pragma unroll
      for (int c = 0; c < 2; ++c) {
        int i = tid + c * 256, r = i >> 3, ch = i & 7;
        *(uint4*)&b_lds[cur ^ 1][r * ROWP + ch * 8] = breg[c];
      }
    } else if (do_b2) {
      int r = tid >> 2, ch = tid & 3;
      *(uint4*)&b_lds[cur ^ 1][r * ROWP + ch * 8] = breg[0];
    }
    __syncthreads();
  }
  // ---- extra K-step: b2 term (A = s rows, B = b2^T in b_lds[0]) ----
  if (do_b2) {
#pragma unroll
    for (int mt = 0; mt < 4; ++mt) {
      h8 a = *(const h8*)&s_lds[(wv * 64 + mt * 16 + m0) * SROW + quad * 8];
#pragma unroll
      for (int ct = 0; ct < 4; ++ct) {
        h8 b = *(const h8*)&b_lds[0][(ct * 16 + m0) * ROWP + quad * 8];
        acc[mt][ct] = __builtin_amdgcn_mfma_f32_16x16x32_f16(a, b, acc[mt][ct], 0, 0, 0);
      }
    }
  }
  // ---- epilogue: coalesced scatter-add ----
#pragma unroll
  for (int mt = 0; mt < 4; ++mt) {
#pragma unroll
    for (int r = 0; r < 4; ++r) {
      int e = eblk + wv * 64 + mt * 16 + quad * 4 + r;
      if (e < N_EDGES) {
        float* ap = agg + (size_t)dst[e] * 64 + m0;
#pragma unroll
        for (int ct = 0; ct < 4; ++ct) atomicAdd(ap + ct * 16, acc[mt][ct][r]);
      }
    }
  }
}

// ================= m + X pack (elementwise) + agg re-zero =================
__global__ void k_mh2(float* __restrict__ agg, const float* __restrict__ deg,
                      const BF* __restrict__ convb, const float* __restrict__ h,
                      _Float16* __restrict__ X) {
  int idx = blockIdx.x * 256 + threadIdx.x;  // N_PAD*64
  int n = idx >> 6, o = idx & 63;
  float m = 0.f, hval = 0.f;
  if (n < N_NODES) {
    float a = agg[idx];
    agg[idx] = 0.f;  // ready for next iteration's atomics
    float inv = 1.f / fmaxf(deg[n], 1.f);
    m = fmaxf(a * inv + ldf(convb, o), 0.f);
    hval = h[idx];
  }
  X[(size_t)n * 128 + o] = (_Float16)m;
  X[(size_t)n * 128 + 64 + o] = (_Float16)hval;
}

// ================= fused GRU =================
__launch_bounds__(256)
__global__ void k_gru(const _Float16* __restrict__ X, const _Float16* __restrict__ W,
                      const float* __restrict__ bcat, float* __restrict__ h) {
  __shared__ _Float16 xa[64 * BROW];
  __shared__ _Float16 wb[256 * BROW];
  __shared__ float bsh[256];
  int tid = threadIdx.x;
  int wv = tid >> 6, ln = tid & 63, m0 = ln & 15, quad = ln >> 4;
  int rowblk = blockIdx.x * 64;
  bsh[tid] = bcat[tid];
#pragma unroll
  for (int c = 0; c < 4; ++c) {
    int i = tid + c * 256, r = i >> 4, ch = i & 15;
    *(uint4*)&xa[r * BROW + ch * 8] = *(const uint4*)(X + (size_t)(rowblk + r) * 128 + ch * 8);
  }
#pragma unroll
  for (int c = 0; c < 16; ++c) {
    int i = tid + c * 256, r = i >> 4, ch = i & 15;
    *(uint4*)&wb[r * BROW + ch * 8] = *(const uint4*)(W + (size_t)r * 128 + ch * 8);
  }
  __syncthreads();
  f4 acc[16];
#pragma unroll
  for (int ct = 0; ct < 16; ++ct)
#pragma unroll
    for (int j = 0; j < 4; ++j) acc[ct][j] = 0.f;
#pragma unroll
  for (int t = 0; t < 4; ++t) {
    h8 a = *(const h8*)&xa[(wv * 16 + m0) * BROW + t * 32 + quad * 8];
#pragma unroll
    for (int ct = 0; ct < 16; ++ct) {
      h8 b = *(const h8*)&wb[(ct * 16 + m0) * BROW + t * 32 + quad * 8];
      acc[ct] = __builtin_amdgcn_mfma_f32_16x16x32_f16(a, b, acc[ct], 0, 0, 0);
    }
  }
#pragma unroll
  for (int c0 = 0; c0 < 4; ++c0) {
    int o = c0 * 16 + m0;
    float br = bsh[o], bz = bsh[64 + o], bn = bsh[128 + o], bh2 = bsh[192 + o];
#pragma unroll
    for (int r = 0; r < 4; ++r) {
      int row = rowblk + wv * 16 + quad * 4 + r;
      if (row < N_NODES) {
        float rr = sigf(acc[c0][r] + br);
        float zz = sigf(acc[c0 + 4][r] + bz);
        float nn = tanh_f(acc[c0 + 8][r] + bn + rr * (acc[c0 + 12][r] + bh2));
        size_t hi = (size_t)row * 64 + o;
        float hp = h[hi];
        h[hi] = (1.f - zz) * nn + zz * hp;
      }
    }
  }
}

// ================= fully fused Set2Set (3 steps + output) =================
__launch_bounds__(256)
__global__ void k_s2s(const float* __restrict__ h, const int* __restrict__ seg,
                      const BF* __restrict__ wih, const BF* __restrict__ whh,
                      const BF* __restrict__ bih, const BF* __restrict__ bhh,
                      float* __restrict__ outp) {
  __shared__ float xrow[128], g[256], qrow[64], hc[64], ccs[64], rr_[64];
  __shared__ float evals[MAXSEG];
  __shared__ float wred[4], rpart[256];
  int b = blockIdx.x, t = threadIdx.x;
  int wv = t >> 6, ln = t & 63;
  if (t < 64) { hc[t] = 0.f; ccs[t] = 0.f; rr_[t] = 0.f; }
  __syncthreads();
  int start = seg[b], end = seg[b + 1];
  int cnt = end - start;
  for (int st = 0; st < 3; ++st) {
    if (t < 64) xrow[t] = hc[t];
    else if (t < 128) xrow[t] = rr_[t - 64];
    __syncthreads();
    {
      float acc = ldf(bih, t) + ldf(bhh, t);
      const BF* wr = wih + t * 128;
      for (int i = 0; i < 128; ++i) acc += xrow[i] * ldf(wr, i);
      const BF* wr2 = whh + t * 64;
      for (int i = 0; i < 64; ++i) acc += xrow[i] * ldf(wr2, i);
      g[t] = acc;
    }
    __syncthreads();
    if (t < 64) {
      float ig = sigf(g[t]), fg = sigf(g[64 + t]);
      float gg = tanh_f(g[128 + t]), og = sigf(g[192 + t]);
      float c = fg * ccs[t] + ig * gg;
      ccs[t] = c;
      float hn = og * tanh_f(c);
      hc[t] = hn;
      qrow[t] = hn;
    }
    __syncthreads();
    // pass 1: e_n = h[n].q, wave-local max
    float mw = -3.4e38f;
    for (int n = start + wv; n < end; n += 4) {
      float p = h[(size_t)n * 64 + ln] * qrow[ln];
#pragma unroll
      for (int off = 32; off > 0; off >>= 1) p += __shfl_xor(p, off);
      if (ln == 0) evals[n - start] = p;
      mw = fmaxf(mw, p);
    }
    if (ln == 0) wred[wv] = mw;
    __syncthreads();
    float gmax = fmaxf(fmaxf(wred[0], wred[1]), fmaxf(wred[2], wred[3]));
    __syncthreads();
    // pass 2: exp + block sum
    float psum = 0.f;
    for (int i = t; i < cnt; i += 256) {
      float a = __expf(evals[i] - gmax);
      evals[i] = a;
      psum += a;
    }
#pragma unroll
    for (int off = 32; off > 0; off >>= 1) psum += __shfl_xor(psum, off);
    if (ln == 0) wred[wv] = psum;
    __syncthreads();
    float inv = 1.f / fmaxf(wred[0] + wred[1] + wred[2] + wred[3], 1e-30f);
    // pass 3: r = sum a_n h[n] * inv
    float racc = 0.f;
    for (int n = start + wv; n < end; n += 4)
      racc += evals[n - start] * h[(size_t)n * 64 + ln];
    rpart[wv * 64 + ln] = racc;
    __syncthreads();
    if (t < 64)
      rr_[t] = (rpart[t] + rpart[64 + t] + rpart[128 + t] + rpart[192 + t]) * inv;
    __syncthreads();
  }
  if (t < 128) outp[b * 128 + t] = (t < 64) ? hc[t] : rr_[t - 64];
}

// ================= launch =================
extern "C" void kernel_launch(void* const* d_in, const int* in_sizes, int n_in,
                              void* d_out, int out_size, void* d_ws, size_t ws_size,
                              hipStream_t stream) {
  const BF* x      = (const BF*)d_in[0];
  const int* ei    = (const int*)d_in[1];
  const BF* ea     = (const BF*)d_in[2];
  const int* batch = (const int*)d_in[3];
  const BF* w0     = (const BF*)d_in[4];
  const BF* b0     = (const BF*)d_in[5];
  const BF* w1     = (const BF*)d_in[6];
  const BF* b1     = (const BF*)d_in[7];
  const BF* w2     = (const BF*)d_in[8];
  const BF* b2     = (const BF*)d_in[9];
  const BF* convb  = (const BF*)d_in[10];
  const BF* gwih   = (const BF*)d_in[11];
  const BF* gwhh   = (const BF*)d_in[12];
  const BF* gbih   = (const BF*)d_in[13];
  const BF* gbhh   = (const BF*)d_in[14];
  const BF* lwih   = (const BF*)d_in[15];
  const BF* lwhh   = (const BF*)d_in[16];
  const BF* lbih   = (const BF*)d_in[17];
  const BF* lbhh   = (const BF*)d_in[18];
  const int* src = ei;
  const int* dstp = ei + N_EDGES;

  char* w = (char*)d_ws;
  size_t off = 0;
  auto take = [&](size_t bytes) -> void* {
    void* p = w + off;
    off = (off + bytes + 255) & ~(size_t)255;
    return p;
  };
  _Float16* Qf16 = (_Float16*)take((size_t)4096 * 128 * 2);
  _Float16* hidf = (_Float16*)take((size_t)E_PAD * 128 * 2);
  float* h       = (float*)take((size_t)N_NODES * 64 * 4);
  float* dz      = (float*)take((size_t)(20000 + N_NODES * 64) * 4);  // deg | agg, one memset
  float* deg     = dz;
  float* agg     = dz + 20000;
  _Float16* X    = (_Float16*)take((size_t)N_PAD * 128 * 2);
  _Float16* Wcat = (_Float16*)take((size_t)256 * 128 * 2);
  float* bcat    = (float*)take((size_t)256 * 4);
  _Float16* b2t  = (_Float16*)take((size_t)2 * 64 * 32 * 2);
  int*   seg     = (int*)take((size_t)129 * 4);

  hipMemsetAsync(dz, 0, (size_t)(20000 + N_NODES * 64) * 4, stream);
  k_prep<<<PREP_BLOCKS, 256, 0, stream>>>(x, ea, batch, dstp, w0, b0, w1, b1, w2, b2,
                                          gwih, gwhh, gbih, gbhh,
                                          h, hidf, Qf16, Wcat, bcat, b2t, seg, deg);
  for (int it = 0; it < 3; ++it) {
    k_msg<<<dim3(E_PAD / 256, 2, 2), 256, 0, stream>>>(h, hidf, Qf16, b2t, src, dstp, agg);
    k_mh2<<<N_PAD * 64 / 256, 256, 0, stream>>>(agg, deg, convb, h, X);
    k_gru<<<N_PAD / 64, 256, 0, stream>>>(X, Wcat, bcat, h);
  }
  k_s2s<<<128, 256, 0, stream>>>(h, seg, lwih, lwhh, lbih, lbhh, (float*)d_out);
}

// Round 5
// 573.893 us; speedup vs baseline: 1.7864x; 1.0027x over previous
//
#include <hip/hip_runtime.h>
#include <hip/hip_bf16.h>

typedef float BF;
__device__ __forceinline__ float ldf(const BF* p, int i) { return p[i]; }

typedef _Float16 h8 __attribute__((ext_vector_type(8)));
typedef float f4 __attribute__((ext_vector_type(4)));

static constexpr int N_NODES = 20000;
static constexpr int N_EDGES = 50000;
static constexpr int E_PAD   = 50176;  // 196*256
static constexpr int N_PAD   = 20032;  // 313*64
static constexpr int BROW    = 136;    // k_gru LDS row (128+8 halves)
static constexpr int ROWP    = 72;     // k_msg B-tile row (64+8 halves)
static constexpr int SROW    = 40;     // k_msg s-tile row (32+8 halves), 80B
static constexpr int MAXSEG  = 2048;

__device__ __forceinline__ float sigf(float x) { return 1.f / (1.f + __expf(-x)); }
__device__ __forceinline__ float tanh_f(float x) {
  float e = __expf(2.f * x);
  return 1.f - 2.f / (e + 1.f);
}

// ================= mega-prep =================
static constexpr int S_LIN0 = 5000;
static constexpr int S_MLP1 = E_PAD * 128 / 256;
static constexpr int S_W2   = 2048;
static constexpr int S_WCAT = 128;
static constexpr int S_B2T  = 16;
static constexpr int S_DEG  = 196;
static constexpr int PREP_BLOCKS = S_LIN0 + S_MLP1 + S_W2 + S_WCAT + S_B2T + 1 + 1 + S_DEG;

__global__ void k_prep(const BF* __restrict__ x, const BF* __restrict__ ea,
                       const int* __restrict__ batch, const int* __restrict__ dst,
                       const BF* __restrict__ w0, const BF* __restrict__ b0,
                       const BF* __restrict__ w1, const BF* __restrict__ b1,
                       const BF* __restrict__ w2, const BF* __restrict__ b2,
                       const BF* __restrict__ gwih, const BF* __restrict__ gwhh,
                       const BF* __restrict__ gbih, const BF* __restrict__ gbhh,
                       float* __restrict__ h, _Float16* __restrict__ hidf,
                       _Float16* __restrict__ Q, _Float16* __restrict__ Wcat,
                       float* __restrict__ bcat, _Float16* __restrict__ b2t,
                       int* __restrict__ seg, float* __restrict__ deg) {
  int bid = blockIdx.x, t = threadIdx.x;
  if (bid < S_LIN0) {
    int idx = bid * 256 + t, n = idx >> 6, o = idx & 63;
    float acc = ldf(b0, o);
#pragma unroll
    for (int f = 0; f < 16; ++f) acc += ldf(x, n * 16 + f) * ldf(w0, o * 16 + f);
    h[idx] = fmaxf(acc, 0.f);
    return;
  }
  bid -= S_LIN0;
  if (bid < S_MLP1) {
    int idx = bid * 256 + t, e = idx >> 7, j = idx & 127;
    float v = 0.f;
    if (e < N_EDGES) {
      float acc = ldf(b1, j);
#pragma unroll
      for (int i = 0; i < 5; ++i) acc += ldf(ea, e * 5 + i) * ldf(w1, j * 5 + i);
      v = fmaxf(acc, 0.f);
    }
    hidf[idx] = (_Float16)v;
    return;
  }
  bid -= S_MLP1;
  if (bid < S_W2) {
    int i = bid * 256 + t;
    Q[i] = (_Float16)ldf(w2, i);
    return;
  }
  bid -= S_W2;
  if (bid < S_WCAT) {
    int idx = bid * 256 + t, row = idx >> 7, k = idx & 127;
    int g = row >> 6, rr = row & 63;
    float v = 0.f;
    if (g == 0) v = (k < 64) ? ldf(gwih, rr * 64 + k) : ldf(gwhh, rr * 64 + (k - 64));
    else if (g == 1) v = (k < 64) ? ldf(gwih, (64 + rr) * 64 + k) : ldf(gwhh, (64 + rr) * 64 + (k - 64));
    else if (g == 2) v = (k < 64) ? ldf(gwih, (128 + rr) * 64 + k) : 0.f;
    else v = (k < 64) ? 0.f : ldf(gwhh, (128 + rr) * 64 + (k - 64));
    Wcat[idx] = (_Float16)v;
    return;
  }
  bid -= S_WCAT;
  if (bid < S_B2T) {
    int idx = bid * 256 + t;
    int y = idx >> 11, rem = idx & 2047, o = rem >> 5, kk = rem & 31;
    b2t[idx] = (_Float16)ldf(b2, (y * 32 + kk) * 64 + o);
    return;
  }
  bid -= S_B2T;
  if (bid == 0) {
    float v;
    if (t < 128) v = ldf(gbih, t) + ldf(gbhh, t);
    else if (t < 192) v = ldf(gbih, t);
    else v = ldf(gbhh, t - 64);
    bcat[t] = v;
    return;
  }
  bid -= 1;
  if (bid == 0) {
    if (t > 128) return;
    if (t == 128) { seg[128] = N_NODES; return; }
    int lo = 0, hi = N_NODES;
    while (lo < hi) {
      int mid = (lo + hi) >> 1;
      if (batch[mid] < t) lo = mid + 1; else hi = mid;
    }
    seg[t] = lo;
    return;
  }
  bid -= 1;
  {
    int e = bid * 256 + t;
    if (e < N_EDGES) atomicAdd(&deg[dst[e]], 1.f);
  }
}

// ================= fused NNConv message kernel v4 =================
// grid (196, 2, 2): y = d-half, z = k-half. block = 256 edges, 4 waves.
// Wave decomposition 2x2: ep = edge-half (128 edges, 8 m-tiles),
// cp = output-half (32 outputs, 2 ct). Halves per-wave LDS B-traffic vs v3.
__launch_bounds__(256, 2)
__global__ void k_msg(const float* __restrict__ h, const _Float16* __restrict__ hidf,
                      const _Float16* __restrict__ Q, const _Float16* __restrict__ b2t,
                      const int* __restrict__ src, const int* __restrict__ dst,
                      float* __restrict__ agg) {
  __shared__ _Float16 s_lds[256 * SROW];
  __shared__ _Float16 b_lds[2][64 * ROWP];
  const int tid = threadIdx.x;
  const int wv = tid >> 6, ln = tid & 63;
  const int ep = wv >> 1, cp = wv & 1;
  const int m0 = ln & 15, quad = ln >> 4;
  const int eblk = blockIdx.x * 256;
  const int dbase = blockIdx.y * 32;
  const int kbase = blockIdx.z * 64;
  const bool do_b2 = (blockIdx.z == 0);

  // ---- stage s: one thread per edge, 32 d-cols of this half ----
  {
    int e = eblk + tid;
    _Float16 sv[32];
    if (e < N_EDGES) {
      const float4* hr = (const float4*)(h + (size_t)src[e] * 64 + dbase);
#pragma unroll
      for (int c = 0; c < 8; ++c) {
        float4 f = hr[c];
        sv[c * 4 + 0] = (_Float16)f.x; sv[c * 4 + 1] = (_Float16)f.y;
        sv[c * 4 + 2] = (_Float16)f.z; sv[c * 4 + 3] = (_Float16)f.w;
      }
    } else {
#pragma unroll
      for (int i = 0; i < 32; ++i) sv[i] = (_Float16)0.f;
    }
#pragma unroll
    for (int c = 0; c < 4; ++c)
      *(uint4*)&s_lds[tid * SROW + c * 8] = *(const uint4*)&sv[c * 8];
  }
  // ---- per-lane hidden fragments: 8 m-tiles x 2 k-steps ----
  h8 hv[8][2];
#pragma unroll
  for (int mt = 0; mt < 8; ++mt) {
    int e = eblk + ep * 128 + mt * 16 + m0;
    const _Float16* hp = hidf + (size_t)e * 128 + kbase + quad * 8;
    hv[mt][0] = *(const h8*)hp;
    hv[mt][1] = *(const h8*)(hp + 32);
  }
  // ---- stage B-tile dl=0 ----
  uint4 breg[2];
  {
    const _Float16* qb = Q + (size_t)dbase * 8192 + kbase;
#pragma unroll
    for (int c = 0; c < 2; ++c) {
      int i = tid + c * 256, r = i >> 3, ch = i & 7;
      breg[c] = *(const uint4*)(qb + (size_t)r * 128 + ch * 8);
    }
#pragma unroll
    for (int c = 0; c < 2; ++c) {
      int i = tid + c * 256, r = i >> 3, ch = i & 7;
      *(uint4*)&b_lds[0][r * ROWP + ch * 8] = breg[c];
    }
  }
  __syncthreads();

  f4 acc[8][2];
#pragma unroll
  for (int mt = 0; mt < 8; ++mt)
#pragma unroll
    for (int ct = 0; ct < 2; ++ct)
#pragma unroll
      for (int j = 0; j < 4; ++j) acc[mt][ct][j] = 0.f;

  for (int dl = 0; dl < 32; ++dl) {
    int cur = dl & 1;
    if (dl + 1 < 32) {
      const _Float16* qb = Q + (size_t)(dbase + dl + 1) * 8192 + kbase;
#pragma unroll
      for (int c = 0; c < 2; ++c) {
        int i = tid + c * 256, r = i >> 3, ch = i & 7;
        breg[c] = *(const uint4*)(qb + (size_t)r * 128 + ch * 8);
      }
    } else if (do_b2) {
      int r = tid >> 2, ch = tid & 3;
      breg[0] = *(const uint4*)(b2t + dbase * 64 + r * 32 + ch * 8);
    }
    _Float16 sv[8];
#pragma unroll
    for (int mt = 0; mt < 8; ++mt)
      sv[mt] = s_lds[(ep * 128 + mt * 16 + m0) * SROW + dl];
#pragma unroll
    for (int t = 0; t < 2; ++t) {
      h8 a[8];
#pragma unroll
      for (int mt = 0; mt < 8; ++mt) a[mt] = hv[mt][t] * sv[mt];
#pragma unroll
      for (int ct = 0; ct < 2; ++ct) {
        h8 b = *(const h8*)&b_lds[cur][(cp * 32 + ct * 16 + m0) * ROWP + t * 32 + quad * 8];
#pragma unroll
        for (int mt = 0; mt < 8; ++mt)
          acc[mt][ct] = __builtin_amdgcn_mfma_f32_16x16x32_f16(a[mt], b, acc[mt][ct], 0, 0, 0);
      }
    }
    if (dl + 1 < 32) {
#pragma unroll
      for (int c = 0; c < 2; ++c) {
        int i = tid + c * 256, r = i >> 3, ch = i & 7;
        *(uint4*)&b_lds[cur ^ 1][r * ROWP + ch * 8] = breg[c];
      }
    } else if (do_b2) {
      int r = tid >> 2, ch = tid & 3;
      *(uint4*)&b_lds[cur ^ 1][r * ROWP + ch * 8] = breg[0];
    }
    __syncthreads();
  }
  // ---- extra K-step: b2 term (A = s rows, B = b2^T in b_lds[0]) ----
  if (do_b2) {
#pragma unroll
    for (int mt = 0; mt < 8; ++mt) {
      h8 a = *(const h8*)&s_lds[(ep * 128 + mt * 16 + m0) * SROW + quad * 8];
#pragma unroll
      for (int ct = 0; ct < 2; ++ct) {
        h8 b = *(const h8*)&b_lds[0][(cp * 32 + ct * 16 + m0) * ROWP + quad * 8];
        acc[mt][ct] = __builtin_amdgcn_mfma_f32_16x16x32_f16(a, b, acc[mt][ct], 0, 0, 0);
      }
    }
  }
  // ---- epilogue: coalesced scatter-add ----
#pragma unroll
  for (int mt = 0; mt < 8; ++mt) {
#pragma unroll
    for (int r = 0; r < 4; ++r) {
      int e = eblk + ep * 128 + mt * 16 + quad * 4 + r;
      if (e < N_EDGES) {
        float* ap = agg + (size_t)dst[e] * 64 + cp * 32 + m0;
        atomicAdd(ap, acc[mt][0][r]);
        atomicAdd(ap + 16, acc[mt][1][r]);
      }
    }
  }
}

// ================= fused m-build + GRU =================
// Builds X-tile [f16(m)|f16(h)] in LDS from agg/deg/h (no X buffer),
// re-zeros agg for the next iteration, then gates via MFMA.
__launch_bounds__(256)
__global__ void k_gru(float* __restrict__ agg, const float* __restrict__ deg,
                      const BF* __restrict__ convb, const _Float16* __restrict__ W,
                      const float* __restrict__ bcat, float* __restrict__ h) {
  __shared__ _Float16 xa[64 * BROW];
  __shared__ _Float16 wb[256 * BROW];
  __shared__ float bsh[256];
  int tid = threadIdx.x;
  int wv = tid >> 6, ln = tid & 63, m0 = ln & 15, quad = ln >> 4;
  int rowblk = blockIdx.x * 64;
  bsh[tid] = bcat[tid];
  // build X rows: thread -> (row, 16-col slice)
  {
    int r = tid >> 2, c0 = (tid & 3) * 16;
    int node = rowblk + r;
    _Float16 mv[16], hv[16];
    if (node < N_NODES) {
      float inv = 1.f / fmaxf(deg[node], 1.f);
      float* ap = agg + (size_t)node * 64 + c0;
      const float* hp = h + (size_t)node * 64 + c0;
#pragma unroll
      for (int i = 0; i < 16; i += 4) {
        float4 a = *(float4*)(ap + i);
        *(float4*)(ap + i) = make_float4(0.f, 0.f, 0.f, 0.f);  // re-zero for next iter
        float4 hf = *(const float4*)(hp + i);
        mv[i + 0] = (_Float16)fmaxf(a.x * inv + ldf(convb, c0 + i + 0), 0.f);
        mv[i + 1] = (_Float16)fmaxf(a.y * inv + ldf(convb, c0 + i + 1), 0.f);
        mv[i + 2] = (_Float16)fmaxf(a.z * inv + ldf(convb, c0 + i + 2), 0.f);
        mv[i + 3] = (_Float16)fmaxf(a.w * inv + ldf(convb, c0 + i + 3), 0.f);
        hv[i + 0] = (_Float16)hf.x; hv[i + 1] = (_Float16)hf.y;
        hv[i + 2] = (_Float16)hf.z; hv[i + 3] = (_Float16)hf.w;
      }
    } else {
#pragma unroll
      for (int i = 0; i < 16; ++i) { mv[i] = (_Float16)0.f; hv[i] = (_Float16)0.f; }
    }
    *(uint4*)&xa[r * BROW + c0] = *(const uint4*)&mv[0];
    *(uint4*)&xa[r * BROW + c0 + 8] = *(const uint4*)&mv[8];
    *(uint4*)&xa[r * BROW + 64 + c0] = *(const uint4*)&hv[0];
    *(uint4*)&xa[r * BROW + 64 + c0 + 8] = *(const uint4*)&hv[8];
  }
#pragma unroll
  for (int c = 0; c < 16; ++c) {
    int i = tid + c * 256, r = i >> 4, ch = i & 15;
    *(uint4*)&wb[r * BROW + ch * 8] = *(const uint4*)(W + (size_t)r * 128 + ch * 8);
  }
  __syncthreads();
  f4 acc[16];
#pragma unroll
  for (int ct = 0; ct < 16; ++ct)
#pragma unroll
    for (int j = 0; j < 4; ++j) acc[ct][j] = 0.f;
#pragma unroll
  for (int t = 0; t < 4; ++t) {
    h8 a = *(const h8*)&xa[(wv * 16 + m0) * BROW + t * 32 + quad * 8];
#pragma unroll
    for (int ct = 0; ct < 16; ++ct) {
      h8 b = *(const h8*)&wb[(ct * 16 + m0) * BROW + t * 32 + quad * 8];
      acc[ct] = __builtin_amdgcn_mfma_f32_16x16x32_f16(a, b, acc[ct], 0, 0, 0);
    }
  }
#pragma unroll
  for (int c0 = 0; c0 < 4; ++c0) {
    int o = c0 * 16 + m0;
    float br = bsh[o], bz = bsh[64 + o], bn = bsh[128 + o], bh2 = bsh[192 + o];
#pragma unroll
    for (int r = 0; r < 4; ++r) {
      int row = rowblk + wv * 16 + quad * 4 + r;
      if (row < N_NODES) {
        float rr = sigf(acc[c0][r] + br);
        float zz = sigf(acc[c0 + 4][r] + bz);
        float nn = tanh_f(acc[c0 + 8][r] + bn + rr * (acc[c0 + 12][r] + bh2));
        size_t hi = (size_t)row * 64 + o;
        float hp = h[hi];
        h[hi] = (1.f - zz) * nn + zz * hp;
      }
    }
  }
}

// ================= fully fused Set2Set (3 steps + output) =================
__launch_bounds__(256)
__global__ void k_s2s(const float* __restrict__ h, const int* __restrict__ seg,
                      const BF* __restrict__ wih, const BF* __restrict__ whh,
                      const BF* __restrict__ bih, const BF* __restrict__ bhh,
                      float* __restrict__ outp) {
  __shared__ float xrow[128], g[256], qrow[64], hc[64], ccs[64], rr_[64];
  __shared__ float evals[MAXSEG];
  __shared__ float wred[4], rpart[256];
  int b = blockIdx.x, t = threadIdx.x;
  int wv = t >> 6, ln = t & 63;
  if (t < 64) { hc[t] = 0.f; ccs[t] = 0.f; rr_[t] = 0.f; }
  __syncthreads();
  int start = seg[b], end = seg[b + 1];
  int cnt = end - start;
  for (int st = 0; st < 3; ++st) {
    if (t < 64) xrow[t] = hc[t];
    else if (t < 128) xrow[t] = rr_[t - 64];
    __syncthreads();
    {
      float acc = ldf(bih, t) + ldf(bhh, t);
      const BF* wr = wih + t * 128;
      for (int i = 0; i < 128; ++i) acc += xrow[i] * ldf(wr, i);
      const BF* wr2 = whh + t * 64;
      for (int i = 0; i < 64; ++i) acc += xrow[i] * ldf(wr2, i);
      g[t] = acc;
    }
    __syncthreads();
    if (t < 64) {
      float ig = sigf(g[t]), fg = sigf(g[64 + t]);
      float gg = tanh_f(g[128 + t]), og = sigf(g[192 + t]);
      float c = fg * ccs[t] + ig * gg;
      ccs[t] = c;
      float hn = og * tanh_f(c);
      hc[t] = hn;
      qrow[t] = hn;
    }
    __syncthreads();
    float mw = -3.4e38f;
    for (int n = start + wv; n < end; n += 4) {
      float p = h[(size_t)n * 64 + ln] * qrow[ln];
#pragma unroll
      for (int off = 32; off > 0; off >>= 1) p += __shfl_xor(p, off);
      if (ln == 0) evals[n - start] = p;
      mw = fmaxf(mw, p);
    }
    if (ln == 0) wred[wv] = mw;
    __syncthreads();
    float gmax = fmaxf(fmaxf(wred[0], wred[1]), fmaxf(wred[2], wred[3]));
    __syncthreads();
    float psum = 0.f;
    for (int i = t; i < cnt; i += 256) {
      float a = __expf(evals[i] - gmax);
      evals[i] = a;
      psum += a;
    }
#pragma unroll
    for (int off = 32; off > 0; off >>= 1) psum += __shfl_xor(psum, off);
    if (ln == 0) wred[wv] = psum;
    __syncthreads();
    float inv = 1.f / fmaxf(wred[0] + wred[1] + wred[2] + wred[3], 1e-30f);
    float racc = 0.f;
    for (int n = start + wv; n < end; n += 4)
      racc += evals[n - start] * h[(size_t)n * 64 + ln];
    rpart[wv * 64 + ln] = racc;
    __syncthreads();
    if (t < 64)
      rr_[t] = (rpart[t] + rpart[64 + t] + rpart[128 + t] + rpart[192 + t]) * inv;
    __syncthreads();
  }
  if (t < 128) outp[b * 128 + t] = (t < 64) ? hc[t] : rr_[t - 64];
}

// ================= launch =================
extern "C" void kernel_launch(void* const* d_in, const int* in_sizes, int n_in,
                              void* d_out, int out_size, void* d_ws, size_t ws_size,
                              hipStream_t stream) {
  const BF* x      = (const BF*)d_in[0];
  const int* ei    = (const int*)d_in[1];
  const BF* ea     = (const BF*)d_in[2];
  const int* batch = (const int*)d_in[3];
  const BF* w0     = (const BF*)d_in[4];
  const BF* b0     = (const BF*)d_in[5];
  const BF* w1     = (const BF*)d_in[6];
  const BF* b1     = (const BF*)d_in[7];
  const BF* w2     = (const BF*)d_in[8];
  const BF* b2     = (const BF*)d_in[9];
  const BF* convb  = (const BF*)d_in[10];
  const BF* gwih   = (const BF*)d_in[11];
  const BF* gwhh   = (const BF*)d_in[12];
  const BF* gbih   = (const BF*)d_in[13];
  const BF* gbhh   = (const BF*)d_in[14];
  const BF* lwih   = (const BF*)d_in[15];
  const BF* lwhh   = (const BF*)d_in[16];
  const BF* lbih   = (const BF*)d_in[17];
  const BF* lbhh   = (const BF*)d_in[18];
  const int* src = ei;
  const int* dstp = ei + N_EDGES;

  char* w = (char*)d_ws;
  size_t off = 0;
  auto take = [&](size_t bytes) -> void* {
    void* p = w + off;
    off = (off + bytes + 255) & ~(size_t)255;
    return p;
  };
  _Float16* Qf16 = (_Float16*)take((size_t)4096 * 128 * 2);
  _Float16* hidf = (_Float16*)take((size_t)E_PAD * 128 * 2);
  float* h       = (float*)take((size_t)N_NODES * 64 * 4);
  float* dz      = (float*)take((size_t)(20000 + N_NODES * 64) * 4);  // deg | agg
  float* deg     = dz;
  float* agg     = dz + 20000;
  _Float16* Wcat = (_Float16*)take((size_t)256 * 128 * 2);
  float* bcat    = (float*)take((size_t)256 * 4);
  _Float16* b2t  = (_Float16*)take((size_t)2 * 64 * 32 * 2);
  int*   seg     = (int*)take((size_t)129 * 4);

  hipMemsetAsync(dz, 0, (size_t)(20000 + N_NODES * 64) * 4, stream);
  k_prep<<<PREP_BLOCKS, 256, 0, stream>>>(x, ea, batch, dstp, w0, b0, w1, b1, w2, b2,
                                          gwih, gwhh, gbih, gbhh,
                                          h, hidf, Qf16, Wcat, bcat, b2t, seg, deg);
  for (int it = 0; it < 3; ++it) {
    k_msg<<<dim3(E_PAD / 256, 2, 2), 256, 0, stream>>>(h, hidf, Qf16, b2t, src, dstp, agg);
    k_gru<<<N_PAD / 64, 256, 0, stream>>>(agg, deg, convb, Wcat, bcat, h);
  }
  k_s2s<<<128, 256, 0, stream>>>(h, seg, lwih, lwhh, lbih, lbhh, (float*)d_out);
}